// Round 25
// baseline (84.278 us; speedup 1.0000x reference)
//
#include <hip/hip_runtime.h>
#include <stdint.h>

typedef __attribute__((ext_vector_type(8))) _Float16 f16x8;
typedef __attribute__((ext_vector_type(4))) float f32x4;
typedef __attribute__((ext_vector_type(2))) float f32x2;

#define S_ 4096
#define D_ 1024
#define NROWS 16384          // B*S
#define QSCALE 0.045084220f  // (1/sqrt(1024)) * log2(e): Q pre-scale -> exp2 softmax
#define EXP2(x) __builtin_amdgcn_exp2f(x)   // raw v_exp_f32 (2^x)

// ---------------------------------------------------------------------------
// Tiny pre-pass: Wq|Wk|Wv (3 x 128 x 1024 f32 = 1.5 MB) -> concatenated f16.
// ---------------------------------------------------------------------------
__global__ __launch_bounds__(256) void cvtw(
    const float* __restrict__ Wq, const float* __restrict__ Wk,
    const float* __restrict__ Wv, _Float16* __restrict__ Wh)
{
  int i = (blockIdx.x * 256 + threadIdx.x) * 8;
  const float* src = (i < 131072) ? Wq : ((i < 262144) ? Wk : Wv);
  int off = i & 131071;
  f32x4 a = *(const f32x4*)(src + off);
  f32x4 b = *(const f32x4*)(src + off + 4);
  f16x8 h;
  #pragma unroll
  for (int j = 0; j < 4; ++j) { h[j] = (_Float16)a[j]; h[j + 4] = (_Float16)b[j]; }
  *(f16x8*)(Wh + i) = h;
}

// ---------------------------------------------------------------------------
// Projections (r13-proven, best measured). A staged f32 + cvt-at-fragment;
// B staged f16 (4-bit XOR layout, single ds_read_b128 fragments); Q output
// pre-scaled by QSCALE (softmax runs in log2 domain downstream).
// ---------------------------------------------------------------------------
__global__ __launch_bounds__(256) void gemm_qkv(
    const float* __restrict__ x, const _Float16* __restrict__ Wh,
    _Float16* __restrict__ qk, _Float16* __restrict__ vt)
{
  __shared__ char smem[32768];          // A0 0..8K | B0 8..16K | A1 16..24K | B1 24..32K
  char* Ab[2] = { smem,        smem + 16384 };
  char* Bb[2] = { smem + 8192, smem + 24576 };
  const int tid  = threadIdx.x;
  const int lane = tid & 63, wid = tid >> 6;
  const int g = lane >> 4, l15 = lane & 15;
  const int m0 = blockIdx.x * 64;
  const int by = blockIdx.y;

  const char* pA[2];
  #pragma unroll
  for (int it = 0; it < 2; ++it) {
    int G = it * 256 + tid, row = G >> 3, gg = (G & 7) ^ (row & 7);
    pA[it] = (const char*)x + (size_t)(m0 + row) * 4096 + gg * 16;
  }
  const char* pB[2];
  #pragma unroll
  for (int it = 0; it < 2; ++it) {
    int d = it * 256 + tid;
    int rowhi = d >> 4, tt = (d & 15) ^ (rowhi & 15);
    int row = rowhi * 4 + (tt >> 2), gg = tt & 3;
    pB[it] = (const char*)(Wh + (size_t)by * 131072 + (size_t)row * 1024) + gg * 16;
  }

#define GSTAGE(bi) do {                                                        \
    _Pragma("unroll")                                                          \
    for (int it_ = 0; it_ < 2; ++it_) {                                        \
      __builtin_amdgcn_global_load_lds(pA[it_],                                \
          Ab[bi] + it_ * 4096 + wid * 1024, 16, 0, 0);                         \
      pA[it_] += 128;                                                          \
      __builtin_amdgcn_global_load_lds(pB[it_],                                \
          Bb[bi] + it_ * 4096 + wid * 1024, 16, 0, 0);                         \
      pB[it_] += 64;                                                           \
    }                                                                          \
  } while (0)

  f32x4 acc[4][2] = {};

#define GCOMPUTE(bi) do {                                                      \
    f16x8 af[4], bg[2];                                                        \
    _Pragma("unroll")                                                          \
    for (int mt = 0; mt < 4; ++mt) {                                           \
      int row = mt * 16 + l15;                                                 \
      const char* base = Ab[bi] + row * 128;                                   \
      f32x4 a0 = *(const f32x4*)(base + (((2 * g    ) ^ (row & 7)) << 4));     \
      f32x4 a1 = *(const f32x4*)(base + (((2 * g + 1) ^ (row & 7)) << 4));     \
      _Pragma("unroll")                                                        \
      for (int i = 0; i < 4; ++i) {                                            \
        af[mt][i] = (_Float16)a0[i]; af[mt][i + 4] = (_Float16)a1[i];          \
      }                                                                        \
    }                                                                          \
    _Pragma("unroll")                                                          \
    for (int nt = 0; nt < 2; ++nt) {                                           \
      int row = wid * 32 + nt * 16 + l15;                                      \
      int byte = ((row >> 2) * 256) +                                          \
                 (((((row & 3) << 2) | g) ^ ((row >> 2) & 15)) << 4);          \
      bg[nt] = *(const f16x8*)(Bb[bi] + byte);                                 \
    }                                                                          \
    __builtin_amdgcn_s_setprio(1);                                             \
    _Pragma("unroll")                                                          \
    for (int mt = 0; mt < 4; ++mt)                                             \
      _Pragma("unroll")                                                        \
      for (int nt = 0; nt < 2; ++nt)                                           \
        acc[mt][nt] = __builtin_amdgcn_mfma_f32_16x16x32_f16(af[mt], bg[nt],   \
                                                             acc[mt][nt], 0, 0, 0); \
    __builtin_amdgcn_s_setprio(0);                                             \
  } while (0)

  GSTAGE(0);
  __syncthreads();
  for (int t = 0; t < 32; t += 2) {
    GSTAGE(1);
    GCOMPUTE(0);
    __syncthreads();
    if (t + 2 < 32) GSTAGE(0);
    GCOMPUTE(1);
    __syncthreads();
  }

  if (by < 2) {
    const float sc = (by == 0) ? QSCALE : 1.0f;
    #pragma unroll
    for (int mt = 0; mt < 4; ++mt)
      #pragma unroll
      for (int nt = 0; nt < 2; ++nt)
        #pragma unroll
        for (int r = 0; r < 4; ++r) {
          int row = m0 + mt * 16 + (g << 2) + r;
          int col = by * 128 + wid * 32 + nt * 16 + l15;
          qk[(size_t)row * 256 + col] = (_Float16)(acc[mt][nt][r] * sc);
        }
  } else {
    _Float16* T = (_Float16*)smem;
    #pragma unroll
    for (int mt = 0; mt < 4; ++mt)
      #pragma unroll
      for (int nt = 0; nt < 2; ++nt)
        #pragma unroll
        for (int r = 0; r < 4; ++r)
          T[(mt * 16 + (g << 2) + r) * 128 + wid * 32 + nt * 16 + l15] =
              (_Float16)acc[mt][nt][r];
    __syncthreads();
    const int b = m0 >> 12, s_base = m0 & 4095;
    #pragma unroll
    for (int it = 0; it < 4; ++it) {
      int Wn = it * 256 + tid;
      int f = Wn >> 3, gran = Wn & 7;
      int kk = gran >> 2, q = gran & 3;
      f16x8 v;
      #pragma unroll
      for (int i = 0; i < 8; ++i) {
        int h = i >> 2, j = i & 3;
        v[i] = T[(kk * 32 + h * 16 + q * 4 + j) * 128 + f];
      }
      *(f16x8*)((char*)vt + (size_t)(b * 128 + f) * 8192 + s_base * 2 + gran * 16) = v;
    }
  }
#undef GSTAGE
#undef GCOMPUTE
}

// ---------------------------------------------------------------------------
// Flash attention (r15 variant -- fastest measured attn dispatch: 47.5 us,
// VGPR 60, Occ 33%). 8 waves x 16 q-rows, double-buffered K/V, swapped QK^T,
// permuted-V single-b128 fragments, log2-domain softmax with raw v_exp,
// defer-max THR=8.
// ---------------------------------------------------------------------------
__global__ __launch_bounds__(512, 4) void attn(const _Float16* __restrict__ qk,
                                               const _Float16* __restrict__ vt,
                                               _Float16* __restrict__ pO,
                                               float* __restrict__ pml,
                                               int ntiles)
{
  __shared__ _Float16 K0l[64 * 128], K1l[64 * 128];
  __shared__ _Float16 V0l[64 * 128], V1l[64 * 128];
  const int tid  = threadIdx.x;
  const int lane = tid & 63, wid = tid >> 6;
  const int g = lane >> 4, l15 = lane & 15;
  const int b  = blockIdx.y;
  const int q0 = blockIdx.x * 128;
  const int split = blockIdx.z;
  const int kv_begin = split * (ntiles * 64);

  f16x8 qf[4];
  {
    const size_t qrow = (size_t)(b * S_ + q0 + wid * 16 + l15) * 256;
    #pragma unroll
    for (int kk = 0; kk < 4; ++kk)
      qf[kk] = *(const f16x8*)(qk + qrow + kk * 32 + g * 8);
  }

  const char* gK[2]; const char* gV[2];
  #pragma unroll
  for (int it = 0; it < 2; ++it) {
    int G = it * 512 + tid;
    int row = G >> 4, ch = G & 15;
    gK[it] = (const char*)qk + (size_t)(b * S_ + kv_begin + row) * 512 + 256 +
             (((ch << 4)) ^ ((row & 15) << 4));
    int f = G >> 3, c = G & 7;
    gV[it] = (const char*)vt + (size_t)(b * 128 + f) * 8192 + (kv_begin >> 6) * 128 +
             ((c ^ (f & 7)) << 4);
  }

#define STAGE(Kb, Vb) do {                                                          \
    _Pragma("unroll")                                                               \
    for (int it_ = 0; it_ < 2; ++it_) {                                             \
      __builtin_amdgcn_global_load_lds(gK[it_],                                     \
          (char*)(Kb) + (it_ * 512 + wid * 64) * 16, 16, 0, 0);                     \
      __builtin_amdgcn_global_load_lds(gV[it_],                                     \
          (char*)(Vb) + (it_ * 512 + wid * 64) * 16, 16, 0, 0);                     \
    }                                                                               \
    gK[0] += 32768; gK[1] += 32768; gV[0] += 128; gV[1] += 128;                     \
  } while (0)

  f32x4 oacc[8] = {};
  float m_run = -1e30f, l_run = 0.f;

#define COMPUTE(Kb, Vb) do {                                                        \
    f32x4 sacc[4] = {};                                                             \
    __builtin_amdgcn_s_setprio(1);                                                  \
    _Pragma("unroll")                                                               \
    for (int kk = 0; kk < 4; ++kk) {                                                \
      const char* kb = (const char*)(Kb) + l15 * 256 +                              \
                       (((kk << 6) | (g << 4)) ^ (l15 << 4));                       \
      _Pragma("unroll")                                                             \
      for (int kvt = 0; kvt < 4; ++kvt) {                                           \
        f16x8 kf = *(const f16x8*)(kb + kvt * 4096);                                \
        sacc[kvt] = __builtin_amdgcn_mfma_f32_16x16x32_f16(kf, qf[kk], sacc[kvt],   \
                                                           0, 0, 0);                \
      }                                                                             \
    }                                                                               \
    __builtin_amdgcn_s_setprio(0);                                                  \
    float x0 = fmaxf(fmaxf(sacc[0][0], sacc[0][1]), fmaxf(sacc[0][2], sacc[0][3])); \
    float x1 = fmaxf(fmaxf(sacc[1][0], sacc[1][1]), fmaxf(sacc[1][2], sacc[1][3])); \
    float x2 = fmaxf(fmaxf(sacc[2][0], sacc[2][1]), fmaxf(sacc[2][2], sacc[2][3])); \
    float x3 = fmaxf(fmaxf(sacc[3][0], sacc[3][1]), fmaxf(sacc[3][2], sacc[3][3])); \
    float pmax = fmaxf(fmaxf(x0, x1), fmaxf(x2, x3));                               \
    pmax = fmaxf(pmax, __shfl_xor(pmax, 16));                                       \
    pmax = fmaxf(pmax, __shfl_xor(pmax, 32));                                       \
    if (!__all(pmax - m_run <= 8.0f)) {                                             \
      float m_new = fmaxf(m_run, pmax);                                             \
      float corr  = EXP2(m_run - m_new);                                            \
      l_run *= corr;                                                                \
      m_run  = m_new;                                                               \
      _Pragma("unroll")                                                             \
      for (int r = 0; r < 4; ++r) {                                                 \
        float cr = __builtin_bit_cast(float,                                        \
            __builtin_amdgcn_ds_bpermute((((g << 2) + r) << 2),                     \
                                         __builtin_bit_cast(int, corr)));           \
        _Pragma("unroll")                                                           \
        for (int ft = 0; ft < 8; ++ft) oacc[ft][r] *= cr;                           \
      }                                                                             \
    }                                                                               \
    float psum = 0.f;                                                               \
    f16x8 pa[2];                                                                    \
    _Pragma("unroll")                                                               \
    for (int k2 = 0; k2 < 2; ++k2)                                                  \
      _Pragma("unroll")                                                             \
      for (int i = 0; i < 8; ++i) {                                                 \
        float p = EXP2(sacc[2 * k2 + (i >> 2)][i & 3] - m_run);                     \
        psum += p;                                                                  \
        pa[k2][i] = (_Float16)p;                                                    \
      }                                                                             \
    psum += __shfl_xor(psum, 16);                                                   \
    psum += __shfl_xor(psum, 32);                                                   \
    l_run += psum;                                                                  \
    __builtin_amdgcn_s_setprio(1);                                                  \
    _Pragma("unroll")                                                               \
    for (int k2 = 0; k2 < 2; ++k2) {                                                \
      const char* vb = (const char*)(Vb) + l15 * 128 +                              \
                       (((k2 << 6) | (g << 4)) ^ ((l15 & 7) << 4));                 \
      _Pragma("unroll")                                                             \
      for (int ft = 0; ft < 8; ++ft) {                                              \
        f16x8 vf = *(const f16x8*)(vb + ft * 2048);                                 \
        oacc[ft] = __builtin_amdgcn_mfma_f32_16x16x32_f16(pa[k2], vf, oacc[ft],     \
                                                          0, 0, 0);                 \
      }                                                                             \
    }                                                                               \
    __builtin_amdgcn_s_setprio(0);                                                  \
  } while (0)

  STAGE(K0l, V0l);
  __syncthreads();
  for (int t = 0; t < ntiles; t += 2) {
    STAGE(K1l, V1l);
    COMPUTE(K0l, V0l);
    __syncthreads();
    if (t + 2 < ntiles) STAGE(K0l, V0l);
    COMPUTE(K1l, V1l);
    __syncthreads();
  }

  #pragma unroll
  for (int r = 0; r < 4; ++r) {
    float mr = __builtin_bit_cast(float,
                 __builtin_amdgcn_ds_bpermute((((g << 2) + r) << 2),
                                              __builtin_bit_cast(int, m_run)));
    float lr = __builtin_bit_cast(float,
                 __builtin_amdgcn_ds_bpermute((((g << 2) + r) << 2),
                                              __builtin_bit_cast(int, l_run)));
    float inv = 1.f / lr;
    const int grow = b * S_ + q0 + wid * 16 + (g << 2) + r;
    _Float16* od = pO + ((size_t)split * NROWS + grow) * 128;
    #pragma unroll
    for (int ft = 0; ft < 8; ++ft)
      od[ft * 16 + l15] = (_Float16)(oacc[ft][r] * inv);
    if (l15 == 0)
      *(f32x2*)(pml + ((size_t)split * NROWS + grow) * 2) = f32x2{mr, lr};
  }
#undef STAGE
#undef COMPUTE
}

// ---------------------------------------------------------------------------
// Combine (r15-proven): 16 rows/block, f16x8 reads, f32x4 writes.
// ---------------------------------------------------------------------------
__global__ __launch_bounds__(256) void combine(const _Float16* __restrict__ pO,
                                               const float* __restrict__ pml,
                                               float* __restrict__ out,
                                               int nsplit)
{
  const int tid  = threadIdx.x;
  const int row  = blockIdx.x * 16 + (tid >> 4);
  const int colg = (tid & 15) * 8;

  float M = -1e30f;
  for (int s = 0; s < nsplit; ++s)
    M = fmaxf(M, pml[((size_t)s * NROWS + row) * 2]);
  float den = 0.f;
  float num[8] = {};
  for (int s = 0; s < nsplit; ++s) {
    f32x2 ml = *(const f32x2*)(pml + ((size_t)s * NROWS + row) * 2);
    float w = EXP2(ml.x - M) * ml.y;
    den += w;
    f16x8 o = *(const f16x8*)(pO + ((size_t)s * NROWS + row) * 128 + colg);
    #pragma unroll
    for (int j = 0; j < 8; ++j) num[j] += w * (float)o[j];
  }
  float inv = 1.f / den;
  f32x4 o0, o1;
  #pragma unroll
  for (int j = 0; j < 4; ++j) { o0[j] = num[j] * inv; o1[j] = num[4 + j] * inv; }
  *(f32x4*)(out + (size_t)row * 128 + colg)     = o0;
  *(f32x4*)(out + (size_t)row * 128 + colg + 4) = o1;
}

extern "C" void kernel_launch(void* const* d_in, const int* in_sizes, int n_in,
                              void* d_out, int out_size, void* d_ws, size_t ws_size,
                              hipStream_t stream)
{
  (void)in_sizes; (void)n_in; (void)out_size;
  const float* x  = (const float*)d_in[0];
  const float* Wq = (const float*)d_in[1];
  const float* Wk = (const float*)d_in[2];
  const float* Wv = (const float*)d_in[3];

  char* ws = (char*)d_ws;
  _Float16* qkbuf = (_Float16*)ws;                               // 8.39 MB
  _Float16* vtbuf = (_Float16*)(ws + (size_t)NROWS * 256 * 2);   // 4.19 MB
  const size_t base  = (size_t)NROWS * 256 * 2 + (size_t)4 * 128 * 4096 * 2;
  const size_t perO  = (size_t)NROWS * 128 * 2;                  // 4.19 MB / split (f16)
  const size_t perML = (size_t)NROWS * 2 * 4;                    // 128 KB / split

  int nsplit = 4;
  while (nsplit > 1 && base + (size_t)nsplit * (perO + perML) > ws_size) nsplit >>= 1;

  // Wh (0.79 MB) transient at start of pO region (gemm reads, attn overwrites)
  _Float16* Whb = (_Float16*)(ws + base);
  _Float16* pO  = (_Float16*)(ws + base);
  float*    pml = (float*)(ws + base + (size_t)nsplit * perO);
  float*    out = (float*)d_out;

  cvtw<<<192, 256, 0, stream>>>(Wq, Wk, Wv, Whb);
  dim3 gg(256, 3);
  gemm_qkv<<<gg, 256, 0, stream>>>(x, Whb, qkbuf, vtbuf);
  dim3 ga(S_ / 128, 4, nsplit);
  attn<<<ga, 512, 0, stream>>>(qkbuf, vtbuf, pO, pml, 64 / nsplit);
  combine<<<NROWS / 16, 256, 0, stream>>>(pO, pml, out, nsplit);
}

// Round 26
// 82.906 us; speedup vs baseline: 1.0166x; 1.0166x over previous
//
#include <hip/hip_runtime.h>
#include <stdint.h>

typedef __attribute__((ext_vector_type(8))) _Float16 f16x8;
typedef __attribute__((ext_vector_type(4))) float f32x4;
typedef __attribute__((ext_vector_type(2))) float f32x2;

#define S_ 4096
#define D_ 1024
#define NROWS 16384          // B*S
#define QSCALE 0.045084220f  // (1/sqrt(1024)) * log2(e): Q pre-scale -> exp2 softmax
#define EXP2(x) __builtin_amdgcn_exp2f(x)   // raw v_exp_f32 (2^x)

// ---------------------------------------------------------------------------
// Tiny pre-pass: Wq|Wk|Wv (3 x 128 x 1024 f32 = 1.5 MB) -> concatenated f16.
// ---------------------------------------------------------------------------
__global__ __launch_bounds__(256) void cvtw(
    const float* __restrict__ Wq, const float* __restrict__ Wk,
    const float* __restrict__ Wv, _Float16* __restrict__ Wh)
{
  int i = (blockIdx.x * 256 + threadIdx.x) * 8;
  const float* src = (i < 131072) ? Wq : ((i < 262144) ? Wk : Wv);
  int off = i & 131071;
  f32x4 a = *(const f32x4*)(src + off);
  f32x4 b = *(const f32x4*)(src + off + 4);
  f16x8 h;
  #pragma unroll
  for (int j = 0; j < 4; ++j) { h[j] = (_Float16)a[j]; h[j + 4] = (_Float16)b[j]; }
  *(f16x8*)(Wh + i) = h;
}

// ---------------------------------------------------------------------------
// Projections (r13-proven, best measured). A staged f32 + cvt-at-fragment;
// B staged f16 (4-bit XOR layout, single ds_read_b128 fragments); Q output
// pre-scaled by QSCALE (softmax runs in log2 domain downstream).
// ---------------------------------------------------------------------------
__global__ __launch_bounds__(256) void gemm_qkv(
    const float* __restrict__ x, const _Float16* __restrict__ Wh,
    _Float16* __restrict__ qk, _Float16* __restrict__ vt)
{
  __shared__ char smem[32768];          // A0 0..8K | B0 8..16K | A1 16..24K | B1 24..32K
  char* Ab[2] = { smem,        smem + 16384 };
  char* Bb[2] = { smem + 8192, smem + 24576 };
  const int tid  = threadIdx.x;
  const int lane = tid & 63, wid = tid >> 6;
  const int g = lane >> 4, l15 = lane & 15;
  const int m0 = blockIdx.x * 64;
  const int by = blockIdx.y;

  const char* pA[2];
  #pragma unroll
  for (int it = 0; it < 2; ++it) {
    int G = it * 256 + tid, row = G >> 3, gg = (G & 7) ^ (row & 7);
    pA[it] = (const char*)x + (size_t)(m0 + row) * 4096 + gg * 16;
  }
  const char* pB[2];
  #pragma unroll
  for (int it = 0; it < 2; ++it) {
    int d = it * 256 + tid;
    int rowhi = d >> 4, tt = (d & 15) ^ (rowhi & 15);
    int row = rowhi * 4 + (tt >> 2), gg = tt & 3;
    pB[it] = (const char*)(Wh + (size_t)by * 131072 + (size_t)row * 1024) + gg * 16;
  }

#define GSTAGE(bi) do {                                                        \
    _Pragma("unroll")                                                          \
    for (int it_ = 0; it_ < 2; ++it_) {                                        \
      __builtin_amdgcn_global_load_lds(pA[it_],                                \
          Ab[bi] + it_ * 4096 + wid * 1024, 16, 0, 0);                         \
      pA[it_] += 128;                                                          \
      __builtin_amdgcn_global_load_lds(pB[it_],                                \
          Bb[bi] + it_ * 4096 + wid * 1024, 16, 0, 0);                         \
      pB[it_] += 64;                                                           \
    }                                                                          \
  } while (0)

  f32x4 acc[4][2] = {};

#define GCOMPUTE(bi) do {                                                      \
    f16x8 af[4], bg[2];                                                        \
    _Pragma("unroll")                                                          \
    for (int mt = 0; mt < 4; ++mt) {                                           \
      int row = mt * 16 + l15;                                                 \
      const char* base = Ab[bi] + row * 128;                                   \
      f32x4 a0 = *(const f32x4*)(base + (((2 * g    ) ^ (row & 7)) << 4));     \
      f32x4 a1 = *(const f32x4*)(base + (((2 * g + 1) ^ (row & 7)) << 4));     \
      _Pragma("unroll")                                                        \
      for (int i = 0; i < 4; ++i) {                                            \
        af[mt][i] = (_Float16)a0[i]; af[mt][i + 4] = (_Float16)a1[i];          \
      }                                                                        \
    }                                                                          \
    _Pragma("unroll")                                                          \
    for (int nt = 0; nt < 2; ++nt) {                                           \
      int row = wid * 32 + nt * 16 + l15;                                      \
      int byte = ((row >> 2) * 256) +                                          \
                 (((((row & 3) << 2) | g) ^ ((row >> 2) & 15)) << 4);          \
      bg[nt] = *(const f16x8*)(Bb[bi] + byte);                                 \
    }                                                                          \
    __builtin_amdgcn_s_setprio(1);                                             \
    _Pragma("unroll")                                                          \
    for (int mt = 0; mt < 4; ++mt)                                             \
      _Pragma("unroll")                                                        \
      for (int nt = 0; nt < 2; ++nt)                                           \
        acc[mt][nt] = __builtin_amdgcn_mfma_f32_16x16x32_f16(af[mt], bg[nt],   \
                                                             acc[mt][nt], 0, 0, 0); \
    __builtin_amdgcn_s_setprio(0);                                             \
  } while (0)

  GSTAGE(0);
  __syncthreads();
  for (int t = 0; t < 32; t += 2) {
    GSTAGE(1);
    GCOMPUTE(0);
    __syncthreads();
    if (t + 2 < 32) GSTAGE(0);
    GCOMPUTE(1);
    __syncthreads();
  }

  if (by < 2) {
    const float sc = (by == 0) ? QSCALE : 1.0f;
    #pragma unroll
    for (int mt = 0; mt < 4; ++mt)
      #pragma unroll
      for (int nt = 0; nt < 2; ++nt)
        #pragma unroll
        for (int r = 0; r < 4; ++r) {
          int row = m0 + mt * 16 + (g << 2) + r;
          int col = by * 128 + wid * 32 + nt * 16 + l15;
          qk[(size_t)row * 256 + col] = (_Float16)(acc[mt][nt][r] * sc);
        }
  } else {
    _Float16* T = (_Float16*)smem;
    #pragma unroll
    for (int mt = 0; mt < 4; ++mt)
      #pragma unroll
      for (int nt = 0; nt < 2; ++nt)
        #pragma unroll
        for (int r = 0; r < 4; ++r)
          T[(mt * 16 + (g << 2) + r) * 128 + wid * 32 + nt * 16 + l15] =
              (_Float16)acc[mt][nt][r];
    __syncthreads();
    const int b = m0 >> 12, s_base = m0 & 4095;
    #pragma unroll
    for (int it = 0; it < 4; ++it) {
      int Wn = it * 256 + tid;
      int f = Wn >> 3, gran = Wn & 7;
      int kk = gran >> 2, q = gran & 3;
      f16x8 v;
      #pragma unroll
      for (int i = 0; i < 8; ++i) {
        int h = i >> 2, j = i & 3;
        v[i] = T[(kk * 32 + h * 16 + q * 4 + j) * 128 + f];
      }
      *(f16x8*)((char*)vt + (size_t)(b * 128 + f) * 8192 + s_base * 2 + gran * 16) = v;
    }
  }
#undef GSTAGE
#undef GCOMPUTE
}

// ---------------------------------------------------------------------------
// Flash attention (r16-proven, best measured total). 32 q-rows/wave (two
// 16-row groups, K/V fragments read once feed two MFMAs), log2-domain softmax
// with raw v_exp, defer-max THR=8, per-group (m,l).
// ---------------------------------------------------------------------------
__global__ __launch_bounds__(256, 2) void attn(const _Float16* __restrict__ qk,
                                               const _Float16* __restrict__ vt,
                                               _Float16* __restrict__ pO,
                                               float* __restrict__ pml,
                                               int ntiles)
{
  __shared__ _Float16 K0l[64 * 128], K1l[64 * 128];
  __shared__ _Float16 V0l[64 * 128], V1l[64 * 128];
  const int tid  = threadIdx.x;
  const int lane = tid & 63, wid = tid >> 6;
  const int g = lane >> 4, l15 = lane & 15;
  const int b  = blockIdx.y;
  const int q0 = blockIdx.x * 128;
  const int split = blockIdx.z;
  const int kv_begin = split * (ntiles * 64);

  f16x8 qf0[4], qf1[4];
  {
    const size_t qr0 = (size_t)(b * S_ + q0 + wid * 32 + l15) * 256;
    #pragma unroll
    for (int kk = 0; kk < 4; ++kk) {
      qf0[kk] = *(const f16x8*)(qk + qr0 + kk * 32 + g * 8);
      qf1[kk] = *(const f16x8*)(qk + qr0 + 16 * 256 + kk * 32 + g * 8);
    }
  }

  const char* gK[4]; const char* gV[4];
  #pragma unroll
  for (int it = 0; it < 4; ++it) {
    int G = it * 256 + tid;
    int row = G >> 4, ch = G & 15;
    gK[it] = (const char*)qk + (size_t)(b * S_ + kv_begin + row) * 512 + 256 +
             (((ch << 4)) ^ ((row & 15) << 4));
    int f = G >> 3, c = G & 7;
    gV[it] = (const char*)vt + (size_t)(b * 128 + f) * 8192 + (kv_begin >> 6) * 128 +
             ((c ^ (f & 7)) << 4);
  }

#define STAGE(Kb, Vb) do {                                                          \
    _Pragma("unroll")                                                               \
    for (int it_ = 0; it_ < 4; ++it_) {                                             \
      __builtin_amdgcn_global_load_lds(gK[it_],                                     \
          (char*)(Kb) + (it_ * 256 + wid * 64) * 16, 16, 0, 0);                     \
      __builtin_amdgcn_global_load_lds(gV[it_],                                     \
          (char*)(Vb) + (it_ * 256 + wid * 64) * 16, 16, 0, 0);                     \
      gK[it_] += 32768; gV[it_] += 128;                                             \
    }                                                                               \
  } while (0)

  f32x4 oa0[8] = {}, oa1[8] = {};
  float m0r = -1e30f, l0r = 0.f, m1r = -1e30f, l1r = 0.f;

#define COMPUTE(Kb, Vb) do {                                                        \
    f32x4 s0[4] = {}, s1[4] = {};                                                   \
    __builtin_amdgcn_s_setprio(1);                                                  \
    _Pragma("unroll")                                                               \
    for (int kk = 0; kk < 4; ++kk) {                                                \
      const char* kb = (const char*)(Kb) + l15 * 256 +                              \
                       (((kk << 6) | (g << 4)) ^ (l15 << 4));                       \
      _Pragma("unroll")                                                             \
      for (int kvt = 0; kvt < 4; ++kvt) {                                           \
        f16x8 kf = *(const f16x8*)(kb + kvt * 4096);                                \
        s0[kvt] = __builtin_amdgcn_mfma_f32_16x16x32_f16(kf, qf0[kk], s0[kvt],      \
                                                         0, 0, 0);                  \
        s1[kvt] = __builtin_amdgcn_mfma_f32_16x16x32_f16(kf, qf1[kk], s1[kvt],      \
                                                         0, 0, 0);                  \
      }                                                                             \
    }                                                                               \
    __builtin_amdgcn_s_setprio(0);                                                  \
    float p0 = fmaxf(                                                               \
        fmaxf(fmaxf(fmaxf(s0[0][0], s0[0][1]), fmaxf(s0[0][2], s0[0][3])),          \
              fmaxf(fmaxf(s0[1][0], s0[1][1]), fmaxf(s0[1][2], s0[1][3]))),         \
        fmaxf(fmaxf(fmaxf(s0[2][0], s0[2][1]), fmaxf(s0[2][2], s0[2][3])),          \
              fmaxf(fmaxf(s0[3][0], s0[3][1]), fmaxf(s0[3][2], s0[3][3]))));        \
    float p1 = fmaxf(                                                               \
        fmaxf(fmaxf(fmaxf(s1[0][0], s1[0][1]), fmaxf(s1[0][2], s1[0][3])),          \
              fmaxf(fmaxf(s1[1][0], s1[1][1]), fmaxf(s1[1][2], s1[1][3]))),         \
        fmaxf(fmaxf(fmaxf(s1[2][0], s1[2][1]), fmaxf(s1[2][2], s1[2][3])),          \
              fmaxf(fmaxf(s1[3][0], s1[3][1]), fmaxf(s1[3][2], s1[3][3]))));        \
    p0 = fmaxf(p0, __shfl_xor(p0, 16)); p0 = fmaxf(p0, __shfl_xor(p0, 32));         \
    p1 = fmaxf(p1, __shfl_xor(p1, 16)); p1 = fmaxf(p1, __shfl_xor(p1, 32));         \
    if (!__all((p0 - m0r <= 8.0f) && (p1 - m1r <= 8.0f))) {                         \
      float mn0 = fmaxf(m0r, p0), mn1 = fmaxf(m1r, p1);                             \
      float c0 = EXP2(m0r - mn0), c1 = EXP2(m1r - mn1);                             \
      l0r *= c0; m0r = mn0; l1r *= c1; m1r = mn1;                                   \
      _Pragma("unroll")                                                             \
      for (int r = 0; r < 4; ++r) {                                                 \
        int ad = ((g << 2) + r) << 2;                                               \
        float cr0 = __builtin_bit_cast(float,                                       \
            __builtin_amdgcn_ds_bpermute(ad, __builtin_bit_cast(int, c0)));         \
        float cr1 = __builtin_bit_cast(float,                                       \
            __builtin_amdgcn_ds_bpermute(ad, __builtin_bit_cast(int, c1)));         \
        _Pragma("unroll")                                                           \
        for (int ft = 0; ft < 8; ++ft) {                                            \
          oa0[ft][r] *= cr0; oa1[ft][r] *= cr1;                                     \
        }                                                                           \
      }                                                                             \
    }                                                                               \
    float ps0 = 0.f, ps1 = 0.f;                                                     \
    f16x8 pa0[2], pa1[2];                                                           \
    _Pragma("unroll")                                                               \
    for (int k2 = 0; k2 < 2; ++k2)                                                  \
      _Pragma("unroll")                                                             \
      for (int i = 0; i < 8; ++i) {                                                 \
        float e0 = EXP2(s0[2 * k2 + (i >> 2)][i & 3] - m0r);                        \
        float e1 = EXP2(s1[2 * k2 + (i >> 2)][i & 3] - m1r);                        \
        ps0 += e0; ps1 += e1;                                                       \
        pa0[k2][i] = (_Float16)e0; pa1[k2][i] = (_Float16)e1;                       \
      }                                                                             \
    ps0 += __shfl_xor(ps0, 16); ps0 += __shfl_xor(ps0, 32);                         \
    ps1 += __shfl_xor(ps1, 16); ps1 += __shfl_xor(ps1, 32);                         \
    l0r += ps0; l1r += ps1;                                                         \
    __builtin_amdgcn_s_setprio(1);                                                  \
    _Pragma("unroll")                                                               \
    for (int k2 = 0; k2 < 2; ++k2) {                                                \
      const char* vb = (const char*)(Vb) + l15 * 128 +                              \
                       (((k2 << 6) | (g << 4)) ^ ((l15 & 7) << 4));                 \
      _Pragma("unroll")                                                             \
      for (int ft = 0; ft < 8; ++ft) {                                              \
        f16x8 vf = *(const f16x8*)(vb + ft * 2048);                                 \
        oa0[ft] = __builtin_amdgcn_mfma_f32_16x16x32_f16(pa0[k2], vf, oa0[ft],      \
                                                         0, 0, 0);                  \
        oa1[ft] = __builtin_amdgcn_mfma_f32_16x16x32_f16(pa1[k2], vf, oa1[ft],      \
                                                         0, 0, 0);                  \
      }                                                                             \
    }                                                                               \
    __builtin_amdgcn_s_setprio(0);                                                  \
  } while (0)

  STAGE(K0l, V0l);
  __syncthreads();
  for (int t = 0; t < ntiles; t += 2) {
    STAGE(K1l, V1l);
    COMPUTE(K0l, V0l);
    __syncthreads();
    if (t + 2 < ntiles) STAGE(K0l, V0l);
    COMPUTE(K1l, V1l);
    __syncthreads();
  }

  #pragma unroll
  for (int s = 0; s < 2; ++s) {
    float mrun = s ? m1r : m0r, lrun = s ? l1r : l0r;
    f32x4* oa = s ? oa1 : oa0;
    #pragma unroll
    for (int r = 0; r < 4; ++r) {
      int ad = ((g << 2) + r) << 2;
      float mr = __builtin_bit_cast(float,
                   __builtin_amdgcn_ds_bpermute(ad, __builtin_bit_cast(int, mrun)));
      float lr = __builtin_bit_cast(float,
                   __builtin_amdgcn_ds_bpermute(ad, __builtin_bit_cast(int, lrun)));
      float inv = 1.f / lr;
      const int grow = b * S_ + q0 + wid * 32 + s * 16 + (g << 2) + r;
      _Float16* od = pO + ((size_t)split * NROWS + grow) * 128;
      #pragma unroll
      for (int ft = 0; ft < 8; ++ft)
        od[ft * 16 + l15] = (_Float16)(oa[ft][r] * inv);
      if (l15 == 0)
        *(f32x2*)(pml + ((size_t)split * NROWS + grow) * 2) = f32x2{mr, lr};
    }
  }
#undef STAGE
#undef COMPUTE
}

// ---------------------------------------------------------------------------
// Combine (r15-proven): 16 rows/block, f16x8 reads, f32x4 writes.
// ---------------------------------------------------------------------------
__global__ __launch_bounds__(256) void combine(const _Float16* __restrict__ pO,
                                               const float* __restrict__ pml,
                                               float* __restrict__ out,
                                               int nsplit)
{
  const int tid  = threadIdx.x;
  const int row  = blockIdx.x * 16 + (tid >> 4);
  const int colg = (tid & 15) * 8;

  float M = -1e30f;
  for (int s = 0; s < nsplit; ++s)
    M = fmaxf(M, pml[((size_t)s * NROWS + row) * 2]);
  float den = 0.f;
  float num[8] = {};
  for (int s = 0; s < nsplit; ++s) {
    f32x2 ml = *(const f32x2*)(pml + ((size_t)s * NROWS + row) * 2);
    float w = EXP2(ml.x - M) * ml.y;
    den += w;
    f16x8 o = *(const f16x8*)(pO + ((size_t)s * NROWS + row) * 128 + colg);
    #pragma unroll
    for (int j = 0; j < 8; ++j) num[j] += w * (float)o[j];
  }
  float inv = 1.f / den;
  f32x4 o0, o1;
  #pragma unroll
  for (int j = 0; j < 4; ++j) { o0[j] = num[j] * inv; o1[j] = num[4 + j] * inv; }
  *(f32x4*)(out + (size_t)row * 128 + colg)     = o0;
  *(f32x4*)(out + (size_t)row * 128 + colg + 4) = o1;
}

extern "C" void kernel_launch(void* const* d_in, const int* in_sizes, int n_in,
                              void* d_out, int out_size, void* d_ws, size_t ws_size,
                              hipStream_t stream)
{
  (void)in_sizes; (void)n_in; (void)out_size;
  const float* x  = (const float*)d_in[0];
  const float* Wq = (const float*)d_in[1];
  const float* Wk = (const float*)d_in[2];
  const float* Wv = (const float*)d_in[3];

  char* ws = (char*)d_ws;
  _Float16* qkbuf = (_Float16*)ws;                               // 8.39 MB
  _Float16* vtbuf = (_Float16*)(ws + (size_t)NROWS * 256 * 2);   // 4.19 MB
  const size_t base  = (size_t)NROWS * 256 * 2 + (size_t)4 * 128 * 4096 * 2;
  const size_t perO  = (size_t)NROWS * 128 * 2;                  // 4.19 MB / split (f16)
  const size_t perML = (size_t)NROWS * 2 * 4;                    // 128 KB / split

  int nsplit = 4;
  while (nsplit > 1 && base + (size_t)nsplit * (perO + perML) > ws_size) nsplit >>= 1;

  // Wh (0.79 MB) transient at start of pO region (gemm reads, attn overwrites)
  _Float16* Whb = (_Float16*)(ws + base);
  _Float16* pO  = (_Float16*)(ws + base);
  float*    pml = (float*)(ws + base + (size_t)nsplit * perO);
  float*    out = (float*)d_out;

  cvtw<<<192, 256, 0, stream>>>(Wq, Wk, Wv, Whb);
  dim3 gg(256, 3);
  gemm_qkv<<<gg, 256, 0, stream>>>(x, Whb, qkbuf, vtbuf);
  dim3 ga(S_ / 128, 4, nsplit);
  attn<<<ga, 256, 0, stream>>>(qkbuf, vtbuf, pO, pml, 64 / nsplit);
  combine<<<NROWS / 16, 256, 0, stream>>>(pO, pml, out, nsplit);
}